// Round 14
// baseline (274.589 us; speedup 1.0000x reference)
//
#include <hip/hip_runtime.h>
#include <hip/hip_bf16.h>
#include <math.h>

typedef unsigned short u16;
typedef __attribute__((ext_vector_type(8))) short bf16x8;
typedef __attribute__((ext_vector_type(8))) unsigned short u16x8;
typedef __attribute__((ext_vector_type(4))) float f32x4;
typedef __attribute__((ext_vector_type(4))) unsigned u32x4;
typedef __attribute__((ext_vector_type(2))) unsigned u32x2;

#define N_NODES 100000
#define IN_CH 128
#define HID 256
#define EMB 128
#define N_PAIRS 500000
#define BN_EPS 1e-5f

#define PBM 64  // pairs per block (kernel B); 64 nodes/block (kernel A)

// ---- bf16 helpers ----
__device__ __forceinline__ u16 f2bf(float f) {            // scalar RNE (prep kernel)
    unsigned u = __builtin_bit_cast(unsigned, f);
    unsigned r = u + 0x7FFFu + ((u >> 16) & 1u);
    return (u16)(r >> 16);
}
__device__ __forceinline__ float bf2f(u16 h) {
    unsigned u = ((unsigned)h) << 16;
    return __builtin_bit_cast(float, u);
}
// packed pair conversion -> v_cvt_pk_bf16_f32
__device__ __forceinline__ unsigned pk2(float a, float b) {
    __hip_bfloat162 h = __float22bfloat162_rn(make_float2(a, b));
    unsigned u;
    __builtin_memcpy(&u, &h, sizeof(u));
    return u;
}

// store 8 floats as bf16 at u16-index base
__device__ __forceinline__ void store8(u16* buf, int base, const float* v) {
    u32x4 hv;
    #pragma unroll
    for (int q = 0; q < 4; ++q) hv[q] = pk2(v[2 * q], v[2 * q + 1]);
    *reinterpret_cast<u32x4*>(&buf[base]) = hv;
}

// ---------------------------------------------------------------------------
// Weight prep into MFMA A-operand fragment-linear layout (weights on M-side):
// idx = ((mt*KS + ks)*64 + l)*8 + j ; value = W[k][n], n = mt*16 + (l&15),
// k = ks*32 + (l>>4)*8 + j. SW1/SW2 hi-only (1-product pair kernel);
// W1/W2 node weights keep hi+lo (2-product, z kept accurate).
// ---------------------------------------------------------------------------
__global__ __launch_bounds__(256) void prep_weights(
    const float* __restrict__ SW1, const float* __restrict__ SW2,
    const float* __restrict__ W1,  const float* __restrict__ W2,
    u16* __restrict__ w1h, u16* __restrict__ w2h,
    u16* __restrict__ w1nh, u16* __restrict__ w1nl,
    u16* __restrict__ w2nh, u16* __restrict__ w2nl)
{
    const int tid = blockIdx.x * 256 + threadIdx.x;
    if (tid < 131072) {                       // SW1 frags: 16 mt x 16 ks
        const int j = tid & 7, l = (tid >> 3) & 63, ks = (tid >> 9) & 15, mt = tid >> 13;
        const int n = mt * 16 + (l & 15);
        const int k = ks * 32 + ((l >> 4) << 3) + j;
        w1h[tid] = f2bf(SW1[(size_t)k * HID + n]);
    } else if (tid < 163840) {                // SW2 frags: 8 mt x 8 ks
        const int t2 = tid - 131072;
        const int j = t2 & 7, l = (t2 >> 3) & 63, ks = (t2 >> 9) & 7, mt = t2 >> 12;
        const int n = mt * 16 + (l & 15);
        const int k = ks * 32 + ((l >> 4) << 3) + j;
        w2h[t2] = f2bf(SW2[(size_t)k * (HID / 2) + n]);
    } else if (tid < 196608) {                // W1 node frags: 16 mt x 4 ks
        const int t3 = tid - 163840;
        const int j = t3 & 7, l = (t3 >> 3) & 63, ks = (t3 >> 9) & 3, mt = t3 >> 11;
        const int n = mt * 16 + (l & 15);
        const int k = ks * 32 + ((l >> 4) << 3) + j;
        const float v = W1[(size_t)k * HID + n];
        const u16 h = f2bf(v);
        w1nh[t3] = h;
        w1nl[t3] = f2bf(v - bf2f(h));
    } else if (tid < 229376) {                // W2 node frags: 8 mt x 8 ks
        const int t4 = tid - 196608;
        const int j = t4 & 7, l = (t4 >> 3) & 63, ks = (t4 >> 9) & 7, mt = t4 >> 12;
        const int n = mt * 16 + (l & 15);
        const int k = ks * 32 + ((l >> 4) << 3) + j;
        const float v = W2[(size_t)k * EMB + n];
        const u16 h = f2bf(v);
        w2nh[t4] = h;
        w2nl[t4] = f2bf(v - bf2f(h));
    }
}

// ---------------------------------------------------------------------------
// Kernel A (MFMA): node MLP. 64 nodes/block, 4 waves. Output z in BF16.
// 2-product split (exact weights) to keep z accurate. (unchanged from r13)
// ---------------------------------------------------------------------------
__global__ __launch_bounds__(256) void node_mfma_kernel(
    const float* __restrict__ x,
    const float* __restrict__ x_mean, const float* __restrict__ x_std,
    const float* __restrict__ b1,
    const float* __restrict__ bn_gamma, const float* __restrict__ bn_beta,
    const float* __restrict__ bn_mean,  const float* __restrict__ bn_var,
    const float* __restrict__ b2,
    const u16* __restrict__ w1nh, const u16* __restrict__ w1nl,
    const u16* __restrict__ w2nh, const u16* __restrict__ w2nl,
    u16* __restrict__ z)
{
    __shared__ __align__(16) u16 XF[8192];    // 16 KB: [slot 0..3][nt 0..3][512]
    __shared__ __align__(16) u16 HF[16384];   // 32 KB: [ks2 0..7][nt 0..3][512]

    const int t   = threadIdx.x;
    const int w   = t >> 6;
    const int l   = t & 63;
    const int l15 = l & 15;
    const int l4  = l >> 4;
    const int n0  = blockIdx.x * 64;
    const int nd  = (n0 + l < N_NODES) ? (n0 + l) : (N_NODES - 1);

    // ---- stage xf: thread (w,l) = node l, channels [w*32, w*32+32) ----
    {
        const float* xp = x + (size_t)nd * IN_CH + w * 32;
        float v[32];
        #pragma unroll
        for (int q = 0; q < 8; ++q)
            *reinterpret_cast<float4*>(&v[q * 4]) = *reinterpret_cast<const float4*>(xp + q * 4);
        #pragma unroll
        for (int q = 0; q < 8; ++q) {
            float4 m4 = *reinterpret_cast<const float4*>(x_mean + w * 32 + q * 4);
            float4 s4 = *reinterpret_cast<const float4*>(x_std  + w * 32 + q * 4);
            float mm[4] = {m4.x, m4.y, m4.z, m4.w};
            float ss[4] = {s4.x, s4.y, s4.z, s4.w};
            #pragma unroll
            for (int e = 0; e < 4; ++e) {
                float val = v[q * 4 + e];
                if (!isfinite(val)) val = 0.0f;
                val = (val - mm[e]) / ss[e];
                v[q * 4 + e] = fminf(fmaxf(val, -10.0f), 10.0f);
            }
        }
        #pragma unroll
        for (int q = 0; q < 4; ++q) {
            const int base = (w * 4 + l4) * 512 + (l15 + 16 * q) * 8;
            store8(XF, base, &v[q * 8]);
        }
    }
    __syncthreads();

    // ---- L1: acc[m][nt], wave owns mt {4w..4w+3}, K=128 ----
    f32x4 acc[4][4];
    #pragma unroll
    for (int m = 0; m < 4; ++m)
        #pragma unroll
        for (int nt = 0; nt < 4; ++nt) acc[m][nt] = (f32x4){0.f, 0.f, 0.f, 0.f};

    #pragma unroll
    for (int sl = 0; sl < 4; ++sl) {
        bf16x8 wh[4], wl[4];
        #pragma unroll
        for (int m = 0; m < 4; ++m) {
            const size_t bo = ((size_t)((w * 4 + m) * 4 + sl) * 64 + l) * 8;
            wh[m] = *reinterpret_cast<const bf16x8*>(&w1nh[bo]);
            wl[m] = *reinterpret_cast<const bf16x8*>(&w1nl[bo]);
        }
        bf16x8 fh[4];
        #pragma unroll
        for (int nt = 0; nt < 4; ++nt)
            fh[nt] = *reinterpret_cast<const bf16x8*>(&XF[(sl * 4 + nt) * 512 + l * 8]);
        __builtin_amdgcn_s_setprio(1);
        #pragma unroll
        for (int m = 0; m < 4; ++m)
            #pragma unroll
            for (int nt = 0; nt < 4; ++nt)
                acc[m][nt] = __builtin_amdgcn_mfma_f32_16x16x32_bf16(wh[m], fh[nt], acc[m][nt], 0, 0, 0);
        #pragma unroll
        for (int m = 0; m < 4; ++m)
            #pragma unroll
            for (int nt = 0; nt < 4; ++nt)
                acc[m][nt] = __builtin_amdgcn_mfma_f32_16x16x32_bf16(wl[m], fh[nt], acc[m][nt], 0, 0, 0);
        __builtin_amdgcn_s_setprio(0);
    }

    // ---- epilogue 1: BN + relu -> HF (bf16) ----
    #pragma unroll
    for (int m = 0; m < 4; ++m) {
        const int mt = w * 4 + m;
        const int nb = mt * 16 + l4 * 4;
        float4 b1v = *reinterpret_cast<const float4*>(b1 + nb);
        float4 gv  = *reinterpret_cast<const float4*>(bn_gamma + nb);
        float4 bev = *reinterpret_cast<const float4*>(bn_beta + nb);
        float4 mev = *reinterpret_cast<const float4*>(bn_mean + nb);
        float4 vav = *reinterpret_cast<const float4*>(bn_var + nb);
        float scale[4], shift[4];
        float bb[4] = {b1v.x, b1v.y, b1v.z, b1v.w};
        float gg[4] = {gv.x, gv.y, gv.z, gv.w};
        float be[4] = {bev.x, bev.y, bev.z, bev.w};
        float me[4] = {mev.x, mev.y, mev.z, mev.w};
        float va[4] = {vav.x, vav.y, vav.z, vav.w};
        #pragma unroll
        for (int r = 0; r < 4; ++r) {
            scale[r] = gg[r] * rsqrtf(va[r] + BN_EPS);
            shift[r] = (bb[r] - me[r]) * scale[r] + be[r];
        }
        #pragma unroll
        for (int nt = 0; nt < 4; ++nt) {
            float v[4];
            #pragma unroll
            for (int r = 0; r < 4; ++r)
                v[r] = fmaxf(fmaf(acc[m][nt][r], scale[r], shift[r]), 0.0f);
            u32x2 hv;
            hv[0] = pk2(v[0], v[1]);
            hv[1] = pk2(v[2], v[3]);
            const int base = ((mt >> 1) * 4 + nt) * 512
                           + (l15 + 16 * ((mt & 1) * 2 + (l4 >> 1))) * 8
                           + (l4 & 1) * 4;
            *reinterpret_cast<u32x2*>(&HF[base]) = hv;
        }
    }
    __syncthreads();

    // ---- L2: acc2[m2][nt], wave owns mt2 {2w, 2w+1}, K=256 ----
    f32x4 acc2[2][4];
    #pragma unroll
    for (int m2 = 0; m2 < 2; ++m2)
        #pragma unroll
        for (int nt = 0; nt < 4; ++nt) acc2[m2][nt] = (f32x4){0.f, 0.f, 0.f, 0.f};

    #pragma unroll
    for (int ks2 = 0; ks2 < 8; ++ks2) {
        bf16x8 wh2[2], wl2[2];
        #pragma unroll
        for (int m2 = 0; m2 < 2; ++m2) {
            const size_t bo = ((size_t)((w * 2 + m2) * 8 + ks2) * 64 + l) * 8;
            wh2[m2] = *reinterpret_cast<const bf16x8*>(&w2nh[bo]);
            wl2[m2] = *reinterpret_cast<const bf16x8*>(&w2nl[bo]);
        }
        bf16x8 fh[4];
        #pragma unroll
        for (int nt = 0; nt < 4; ++nt)
            fh[nt] = *reinterpret_cast<const bf16x8*>(&HF[(ks2 * 4 + nt) * 512 + l * 8]);
        __builtin_amdgcn_s_setprio(1);
        #pragma unroll
        for (int m2 = 0; m2 < 2; ++m2)
            #pragma unroll
            for (int nt = 0; nt < 4; ++nt)
                acc2[m2][nt] = __builtin_amdgcn_mfma_f32_16x16x32_bf16(wh2[m2], fh[nt], acc2[m2][nt], 0, 0, 0);
        #pragma unroll
        for (int m2 = 0; m2 < 2; ++m2)
            #pragma unroll
            for (int nt = 0; nt < 4; ++nt)
                acc2[m2][nt] = __builtin_amdgcn_mfma_f32_16x16x32_bf16(wl2[m2], fh[nt], acc2[m2][nt], 0, 0, 0);
        __builtin_amdgcn_s_setprio(0);
    }

    // ---- epilogue 2: z = bf16(relu(acc2 + b2)) -> global ----
    #pragma unroll
    for (int m2 = 0; m2 < 2; ++m2) {
        const int nb2 = (w * 2 + m2) * 16 + l4 * 4;
        float4 b2v = *reinterpret_cast<const float4*>(b2 + nb2);
        float bb[4] = {b2v.x, b2v.y, b2v.z, b2v.w};
        #pragma unroll
        for (int nt = 0; nt < 4; ++nt) {
            const int node = n0 + nt * 16 + l15;
            if (node < N_NODES) {
                float v0 = fmaxf(acc2[m2][nt][0] + bb[0], 0.0f);
                float v1 = fmaxf(acc2[m2][nt][1] + bb[1], 0.0f);
                float v2 = fmaxf(acc2[m2][nt][2] + bb[2], 0.0f);
                float v3 = fmaxf(acc2[m2][nt][3] + bb[3], 0.0f);
                u32x2 hv;
                hv[0] = pk2(v0, v1);
                hv[1] = pk2(v2, v3);
                *reinterpret_cast<u32x2*>(z + (size_t)node * EMB + nb2) = hv;
            }
        }
    }
}

// ---------------------------------------------------------------------------
// Kernel B (MFMA): 64 pairs/block, 8 WAVES (512 thr), r13 math + r9 register
// geometry: wave owns mt {2w,2w+1} (L1, 32 AGPR) and mt2 = w (L2, 16 AGPR) so
// total regs ~<=128 -> 4 waves/SIMD (2x the residency of r13's 4-wave shape).
// Same double-buffered segment schedule, 1-product bf16 MFMA, reg-held rebuild.
// No 2nd __launch_bounds__ arg ((512,4)=>spill r6; (512,2)=>1-block r7).
// ---------------------------------------------------------------------------
__global__ __launch_bounds__(512) void pair_mfma_kernel(
    const u16* __restrict__ z,
    const int* __restrict__ pairs,
    const float* __restrict__ logdeg,
    const u16* __restrict__ w1h,
    const u16* __restrict__ w2h,
    const float* __restrict__ SW1, const float* __restrict__ Sb1,
    const float* __restrict__ Sb2,
    const float* __restrict__ SW3, const float* __restrict__ Sb3,
    float* __restrict__ out)
{
    __shared__ __align__(16) u16 Abuf[8192];   // 16 KB: [slot 0..3][nt 0..3][512]
    __shared__ __align__(16) u16 Bbuf[8192];   // 16 KB
    __shared__ float red[8][4][16];            // 2 KB

    const int t   = threadIdx.x;
    const int w   = t >> 6;        // wave 0..7
    const int l   = t & 63;
    const int l15 = l & 15;
    const int l4  = l >> 4;
    const int p0  = blockIdx.x * PBM;

    // thread (w,l): pair l, channels [w*8, w*8+8) of a 64-ch half.
    // s -> slot w>>2, d -> slot 2+(w>>2); q = w&3 (k = slot*32 + q*8 + j)
    const int baseS = (((w >> 2)) * 4 + l4) * 512 + (l15 + 16 * (w & 3)) * 8;
    const int baseD = ((2 + (w >> 2)) * 4 + l4) * 512 + (l15 + 16 * (w & 3)) * 8;

    const int gp  = (p0 + l < N_PAIRS) ? (p0 + l) : (N_PAIRS - 1);
    const int gsi = pairs[(size_t)gp * 2 + 0];
    const int gdi = pairs[(size_t)gp * 2 + 1];

    // ---- gather both halves (bf16, raw u16x8), stage half-0 -> Abuf ----
    const u16* zs0 = z + (size_t)gsi * EMB + w * 8;
    const u16* zd0 = z + (size_t)gdi * EMB + w * 8;
    u16x8 s0 = *reinterpret_cast<const u16x8*>(zs0);
    u16x8 d0 = *reinterpret_cast<const u16x8*>(zd0);
    u16x8 s1 = *reinterpret_cast<const u16x8*>(zs0 + 64);
    u16x8 d1 = *reinterpret_cast<const u16x8*>(zd0 + 64);

    *reinterpret_cast<u16x8*>(&Abuf[baseS]) = s0;
    *reinterpret_cast<u16x8*>(&Abuf[baseD]) = d0;

    // ---- prefetch epilogue-1 gather data ----
    float ldS[4], ldD[4];
    #pragma unroll
    for (int nt = 0; nt < 4; ++nt) {
        const int pidx = (p0 + nt * 16 + l15 < N_PAIRS) ? (p0 + nt * 16 + l15) : (N_PAIRS - 1);
        ldS[nt] = logdeg[pairs[(size_t)pidx * 2 + 0]];
        ldD[nt] = logdeg[pairs[(size_t)pidx * 2 + 1]];
    }

    __syncthreads();   // bar1

    f32x4 acc[2][4];
    #pragma unroll
    for (int m = 0; m < 2; ++m)
        #pragma unroll
        for (int nt = 0; nt < 4; ++nt) acc[m][nt] = (f32x4){0.f, 0.f, 0.f, 0.f};

    // one 128-K segment; weight register dbuf across sl; 1-product; mt {2w,2w+1}
    auto run_pass = [&](const u16* buf, int k0, int k1, int k2, int k3) {
        const int ksg[4] = {k0, k1, k2, k3};
        bf16x8 wh[2][2];
        #pragma unroll
        for (int m = 0; m < 2; ++m) {
            const size_t bo = ((size_t)((w * 2 + m) * 16 + ksg[0]) * 64 + l) * 8;
            wh[0][m] = *reinterpret_cast<const bf16x8*>(&w1h[bo]);
        }
        #pragma unroll
        for (int sl = 0; sl < 4; ++sl) {
            const int cur = sl & 1;
            if (sl < 3) {
                #pragma unroll
                for (int m = 0; m < 2; ++m) {
                    const size_t bo = ((size_t)((w * 2 + m) * 16 + ksg[sl + 1]) * 64 + l) * 8;
                    wh[cur ^ 1][m] = *reinterpret_cast<const bf16x8*>(&w1h[bo]);
                }
            }
            #pragma unroll
            for (int nh = 0; nh < 2; ++nh) {
                bf16x8 fh[2];
                #pragma unroll
                for (int e = 0; e < 2; ++e)
                    fh[e] = *reinterpret_cast<const bf16x8*>(&buf[(sl * 4 + nh * 2 + e) * 512 + l * 8]);
                __builtin_amdgcn_s_setprio(1);
                #pragma unroll
                for (int m = 0; m < 2; ++m)
                    #pragma unroll
                    for (int e = 0; e < 2; ++e)
                        acc[m][nh * 2 + e] = __builtin_amdgcn_mfma_f32_16x16x32_bf16(wh[cur][m], fh[e], acc[m][nh * 2 + e], 0, 0, 0);
                __builtin_amdgcn_s_setprio(0);
            }
        }
    };

    // rebuild p = s~*d~, ad = |s~-d~| from HELD registers (8 ch)
    auto rebuildR = [&](u16x8 sa, u16x8 da, float* pv, float* av) {
        #pragma unroll
        for (int qq = 0; qq < 8; ++qq) {
            const float s = bf2f(sa[qq]);
            const float d = bf2f(da[qq]);
            pv[qq] = s * d;
            av[qq] = fabsf(s - d);
        }
    };

    // ---- seg0 compute + rebuild(half-0 regs) -> Bbuf ----
    run_pass(Abuf, 0, 1, 4, 5);
    {
        float pv[8], av[8];
        rebuildR(s0, d0, pv, av);
        store8(Bbuf, baseS, pv);
        store8(Bbuf, baseD, av);
    }
    __syncthreads();   // bar2: Bbuf visible; all Abuf reads retired

    // ---- write held half-1 -> Abuf, compute seg2 from Bbuf ----
    *reinterpret_cast<u16x8*>(&Abuf[baseS]) = s1;
    *reinterpret_cast<u16x8*>(&Abuf[baseD]) = d1;
    run_pass(Bbuf, 8, 9, 12, 13);
    __syncthreads();   // bar3: Abuf(half-1) visible; all Bbuf reads retired

    // ---- seg1 compute + rebuild(half-1 regs) -> Bbuf ----
    run_pass(Abuf, 2, 3, 6, 7);
    {
        float pv[8], av[8];
        rebuildR(s1, d1, pv, av);
        store8(Bbuf, baseS, pv);
        store8(Bbuf, baseD, av);
    }
    __syncthreads();   // bar4

    // ---- seg3 compute ----
    run_pass(Bbuf, 10, 11, 14, 15);

    // ---- layer 2: wave w's s1 cols form exactly k-chunk ks2 = w ----
    f32x4 acc2[4];
    #pragma unroll
    for (int nt = 0; nt < 4; ++nt) acc2[nt] = (f32x4){0.f, 0.f, 0.f, 0.f};

    // epilogue-1 for this wave's both m: bias + logdeg rank-2 + relu -> slot w>>1
    auto epi1 = [&](u16* buf) {
        #pragma unroll
        for (int m = 0; m < 2; ++m) {
            const int mt = w * 2 + m;
            const int nb = mt * 16 + l4 * 4;
            float sb[4], wa[4], wb[4];
            *reinterpret_cast<float4*>(sb) = *reinterpret_cast<const float4*>(&Sb1[nb]);
            *reinterpret_cast<float4*>(wa) = *reinterpret_cast<const float4*>(&SW1[(size_t)512 * HID + nb]);
            *reinterpret_cast<float4*>(wb) = *reinterpret_cast<const float4*>(&SW1[(size_t)513 * HID + nb]);
            #pragma unroll
            for (int nt = 0; nt < 4; ++nt) {
                float v[4];
                #pragma unroll
                for (int r = 0; r < 4; ++r) {
                    float x0 = acc[m][nt][r] + sb[r];
                    x0 = fmaf(ldS[nt], wa[r], x0);
                    x0 = fmaf(ldD[nt], wb[r], x0);
                    v[r] = fmaxf(x0, 0.0f);
                }
                u32x2 hv;
                hv[0] = pk2(v[0], v[1]);
                hv[1] = pk2(v[2], v[3]);
                const int base = ((w >> 1) * 4 + nt) * 512
                               + (l15 + 16 * (m * 2 + (l4 >> 1))) * 8
                               + (l4 & 1) * 4;
                *reinterpret_cast<u32x2*>(&buf[base]) = hv;
            }
        }
    };

    // mfma2: slot cs holds ks2 = 2cs + g ; mt2 = w
    auto mfma2 = [&](const u16* buf, int g) {
        #pragma unroll
        for (int cs = 0; cs < 4; ++cs) {
            const int ks2 = cs * 2 + g;
            const size_t bo = ((size_t)(w * 8 + ks2) * 64 + l) * 8;
            bf16x8 wh2 = *reinterpret_cast<const bf16x8*>(&w2h[bo]);
            #pragma unroll
            for (int nh = 0; nh < 2; ++nh) {
                bf16x8 fh[2];
                #pragma unroll
                for (int e = 0; e < 2; ++e)
                    fh[e] = *reinterpret_cast<const bf16x8*>(&buf[(cs * 4 + nh * 2 + e) * 512 + l * 8]);
                __builtin_amdgcn_s_setprio(1);
                #pragma unroll
                for (int e = 0; e < 2; ++e)
                    acc2[nh * 2 + e] = __builtin_amdgcn_mfma_f32_16x16x32_bf16(wh2, fh[e], acc2[nh * 2 + e], 0, 0, 0);
                __builtin_amdgcn_s_setprio(0);
            }
        }
    };

    if ((w & 1) == 0) epi1(Abuf);   // Abuf safe: all reads done before bar4
    __syncthreads();                // bar5: Abuf g=0 frags visible; Bbuf reads retired
    if ((w & 1) == 1) epi1(Bbuf);   // overlaps mfma2(Abuf) below
    mfma2(Abuf, 0);
    __syncthreads();                // bar6: Bbuf g=1 frags visible
    mfma2(Bbuf, 1);

    // ---- epilogue 2 + layer 3: wave w owns cols [w*16, w*16+16) ----
    {
        float part[4] = {0.f, 0.f, 0.f, 0.f};
        const int nb2 = w * 16 + l4 * 4;
        float sb[4], w3[4];
        *reinterpret_cast<float4*>(sb) = *reinterpret_cast<const float4*>(&Sb2[nb2]);
        *reinterpret_cast<float4*>(w3) = *reinterpret_cast<const float4*>(&SW3[nb2]);
        #pragma unroll
        for (int nt = 0; nt < 4; ++nt)
            #pragma unroll
            for (int r = 0; r < 4; ++r)
                part[nt] = fmaf(fmaxf(acc2[nt][r] + sb[r], 0.0f), w3[r], part[nt]);
        #pragma unroll
        for (int nt = 0; nt < 4; ++nt) {
            part[nt] += __shfl_xor(part[nt], 16);
            part[nt] += __shfl_xor(part[nt], 32);
        }
        if (l < 16) {
            #pragma unroll
            for (int nt = 0; nt < 4; ++nt) red[w][nt][l15] = part[nt];
        }
    }
    __syncthreads();   // bar7

    if (t < 64) {
        const int nt = t >> 4, pp = t & 15;
        float v = Sb3[0];
        #pragma unroll
        for (int ww = 0; ww < 8; ++ww) v += red[ww][nt][pp];
        if (isnan(v)) v = 0.0f;
        else if (isinf(v)) v = (v > 0.0f) ? 20.0f : -20.0f;
        const int pidx = p0 + nt * 16 + pp;
        if (pidx < N_PAIRS) out[pidx] = v;
    }
}

// ---------------------------------------------------------------------------
extern "C" void kernel_launch(void* const* d_in, const int* in_sizes, int n_in,
                              void* d_out, int out_size, void* d_ws, size_t ws_size,
                              hipStream_t stream)
{
    const float* x        = (const float*)d_in[0];
    // d_in[1] = edge_index : unused by the reference
    const int*   pairs    = (const int*)d_in[2];
    const float* x_mean   = (const float*)d_in[3];
    const float* x_std    = (const float*)d_in[4];
    const float* logdeg   = (const float*)d_in[5];
    const float* W1       = (const float*)d_in[6];
    const float* b1       = (const float*)d_in[7];
    const float* bn_gamma = (const float*)d_in[8];
    const float* bn_beta  = (const float*)d_in[9];
    const float* bn_mean  = (const float*)d_in[10];
    const float* bn_var   = (const float*)d_in[11];
    const float* W2       = (const float*)d_in[12];
    const float* b2       = (const float*)d_in[13];
    const float* SW1      = (const float*)d_in[14];
    const float* Sb1      = (const float*)d_in[15];
    const float* SW2      = (const float*)d_in[16];
    const float* Sb2      = (const float*)d_in[17];
    const float* SW3      = (const float*)d_in[18];
    const float* Sb3      = (const float*)d_in[19];

    float* outp = (float*)d_out;

    // ws layout (z bf16: 25,600,000 B)
    char* wsb = (char*)d_ws;
    u16* zbuf = (u16*)wsb;
    u16* w1h  = (u16*)(wsb + 25600000);                 // 262144 B
    u16* w2h  = (u16*)(wsb + 25862144);                 // 65536 B
    u16* w1nh = (u16*)(wsb + 25927680);                 // 65536 B
    u16* w1nl = (u16*)(wsb + 25993216);                 // 65536 B
    u16* w2nh = (u16*)(wsb + 26058752);                 // 65536 B
    u16* w2nl = (u16*)(wsb + 26124288);                 // 65536 B (end 26,189,824)

    prep_weights<<<896, 256, 0, stream>>>(SW1, SW2, W1, W2,
                                          w1h, w2h,
                                          w1nh, w1nl, w2nh, w2nl);

    node_mfma_kernel<<<(N_NODES + 63) / 64, 256, 0, stream>>>(
        x, x_mean, x_std, b1, bn_gamma, bn_beta, bn_mean, bn_var, b2,
        w1nh, w1nl, w2nh, w2nl, zbuf);

    pair_mfma_kernel<<<(N_PAIRS + PBM - 1) / PBM, 512, 0, stream>>>(
        zbuf, pairs, logdeg, w1h, w2h, SW1, Sb1, Sb2, SW3, Sb3, outp);
}

// Round 15
// 248.049 us; speedup vs baseline: 1.1070x; 1.1070x over previous
//
#include <hip/hip_runtime.h>
#include <hip/hip_bf16.h>
#include <math.h>

typedef unsigned short u16;
typedef __attribute__((ext_vector_type(8))) short bf16x8;
typedef __attribute__((ext_vector_type(8))) unsigned short u16x8;
typedef __attribute__((ext_vector_type(4))) float f32x4;
typedef __attribute__((ext_vector_type(4))) unsigned u32x4;
typedef __attribute__((ext_vector_type(2))) unsigned u32x2;

#define N_NODES 100000
#define IN_CH 128
#define HID 256
#define EMB 128
#define N_PAIRS 500000
#define BN_EPS 1e-5f

#define PBM 64  // pairs per block (kernel B); 64 nodes/block (kernel A)

// ---- bf16 helpers ----
__device__ __forceinline__ u16 f2bf(float f) {            // scalar RNE (prep kernel)
    unsigned u = __builtin_bit_cast(unsigned, f);
    unsigned r = u + 0x7FFFu + ((u >> 16) & 1u);
    return (u16)(r >> 16);
}
__device__ __forceinline__ float bf2f(u16 h) {
    unsigned u = ((unsigned)h) << 16;
    return __builtin_bit_cast(float, u);
}
// packed pair conversion -> v_cvt_pk_bf16_f32
__device__ __forceinline__ unsigned pk2(float a, float b) {
    __hip_bfloat162 h = __float22bfloat162_rn(make_float2(a, b));
    unsigned u;
    __builtin_memcpy(&u, &h, sizeof(u));
    return u;
}

// store 8 floats as bf16 at u16-index base
__device__ __forceinline__ void store8(u16* buf, int base, const float* v) {
    u32x4 hv;
    #pragma unroll
    for (int q = 0; q < 4; ++q) hv[q] = pk2(v[2 * q], v[2 * q + 1]);
    *reinterpret_cast<u32x4*>(&buf[base]) = hv;
}

// ---------------------------------------------------------------------------
// Weight prep into MFMA A-operand fragment-linear layout (weights on M-side):
// idx = ((mt*KS + ks)*64 + l)*8 + j ; value = W[k][n], n = mt*16 + (l&15),
// k = ks*32 + (l>>4)*8 + j. SW1/SW2 hi-only (1-product pair kernel);
// W1/W2 node weights keep hi+lo (2-product, z kept accurate).
// ---------------------------------------------------------------------------
__global__ __launch_bounds__(256) void prep_weights(
    const float* __restrict__ SW1, const float* __restrict__ SW2,
    const float* __restrict__ W1,  const float* __restrict__ W2,
    u16* __restrict__ w1h, u16* __restrict__ w2h,
    u16* __restrict__ w1nh, u16* __restrict__ w1nl,
    u16* __restrict__ w2nh, u16* __restrict__ w2nl)
{
    const int tid = blockIdx.x * 256 + threadIdx.x;
    if (tid < 131072) {                       // SW1 frags: 16 mt x 16 ks
        const int j = tid & 7, l = (tid >> 3) & 63, ks = (tid >> 9) & 15, mt = tid >> 13;
        const int n = mt * 16 + (l & 15);
        const int k = ks * 32 + ((l >> 4) << 3) + j;
        w1h[tid] = f2bf(SW1[(size_t)k * HID + n]);
    } else if (tid < 163840) {                // SW2 frags: 8 mt x 8 ks
        const int t2 = tid - 131072;
        const int j = t2 & 7, l = (t2 >> 3) & 63, ks = (t2 >> 9) & 7, mt = t2 >> 12;
        const int n = mt * 16 + (l & 15);
        const int k = ks * 32 + ((l >> 4) << 3) + j;
        w2h[t2] = f2bf(SW2[(size_t)k * (HID / 2) + n]);
    } else if (tid < 196608) {                // W1 node frags: 16 mt x 4 ks
        const int t3 = tid - 163840;
        const int j = t3 & 7, l = (t3 >> 3) & 63, ks = (t3 >> 9) & 3, mt = t3 >> 11;
        const int n = mt * 16 + (l & 15);
        const int k = ks * 32 + ((l >> 4) << 3) + j;
        const float v = W1[(size_t)k * HID + n];
        const u16 h = f2bf(v);
        w1nh[t3] = h;
        w1nl[t3] = f2bf(v - bf2f(h));
    } else if (tid < 229376) {                // W2 node frags: 8 mt x 8 ks
        const int t4 = tid - 196608;
        const int j = t4 & 7, l = (t4 >> 3) & 63, ks = (t4 >> 9) & 7, mt = t4 >> 12;
        const int n = mt * 16 + (l & 15);
        const int k = ks * 32 + ((l >> 4) << 3) + j;
        const float v = W2[(size_t)k * EMB + n];
        const u16 h = f2bf(v);
        w2nh[t4] = h;
        w2nl[t4] = f2bf(v - bf2f(h));
    }
}

// ---------------------------------------------------------------------------
// Kernel A (MFMA): node MLP. 64 nodes/block, 4 waves. Output z in BF16.
// 2-product split (exact weights) to keep z accurate. (unchanged from r13)
// ---------------------------------------------------------------------------
__global__ __launch_bounds__(256) void node_mfma_kernel(
    const float* __restrict__ x,
    const float* __restrict__ x_mean, const float* __restrict__ x_std,
    const float* __restrict__ b1,
    const float* __restrict__ bn_gamma, const float* __restrict__ bn_beta,
    const float* __restrict__ bn_mean,  const float* __restrict__ bn_var,
    const float* __restrict__ b2,
    const u16* __restrict__ w1nh, const u16* __restrict__ w1nl,
    const u16* __restrict__ w2nh, const u16* __restrict__ w2nl,
    u16* __restrict__ z)
{
    __shared__ __align__(16) u16 XF[8192];    // 16 KB: [slot 0..3][nt 0..3][512]
    __shared__ __align__(16) u16 HF[16384];   // 32 KB: [ks2 0..7][nt 0..3][512]

    const int t   = threadIdx.x;
    const int w   = t >> 6;
    const int l   = t & 63;
    const int l15 = l & 15;
    const int l4  = l >> 4;
    const int n0  = blockIdx.x * 64;
    const int nd  = (n0 + l < N_NODES) ? (n0 + l) : (N_NODES - 1);

    // ---- stage xf: thread (w,l) = node l, channels [w*32, w*32+32) ----
    {
        const float* xp = x + (size_t)nd * IN_CH + w * 32;
        float v[32];
        #pragma unroll
        for (int q = 0; q < 8; ++q)
            *reinterpret_cast<float4*>(&v[q * 4]) = *reinterpret_cast<const float4*>(xp + q * 4);
        #pragma unroll
        for (int q = 0; q < 8; ++q) {
            float4 m4 = *reinterpret_cast<const float4*>(x_mean + w * 32 + q * 4);
            float4 s4 = *reinterpret_cast<const float4*>(x_std  + w * 32 + q * 4);
            float mm[4] = {m4.x, m4.y, m4.z, m4.w};
            float ss[4] = {s4.x, s4.y, s4.z, s4.w};
            #pragma unroll
            for (int e = 0; e < 4; ++e) {
                float val = v[q * 4 + e];
                if (!isfinite(val)) val = 0.0f;
                val = (val - mm[e]) / ss[e];
                v[q * 4 + e] = fminf(fmaxf(val, -10.0f), 10.0f);
            }
        }
        #pragma unroll
        for (int q = 0; q < 4; ++q) {
            const int base = (w * 4 + l4) * 512 + (l15 + 16 * q) * 8;
            store8(XF, base, &v[q * 8]);
        }
    }
    __syncthreads();

    // ---- L1: acc[m][nt], wave owns mt {4w..4w+3}, K=128 ----
    f32x4 acc[4][4];
    #pragma unroll
    for (int m = 0; m < 4; ++m)
        #pragma unroll
        for (int nt = 0; nt < 4; ++nt) acc[m][nt] = (f32x4){0.f, 0.f, 0.f, 0.f};

    #pragma unroll
    for (int sl = 0; sl < 4; ++sl) {
        bf16x8 wh[4], wl[4];
        #pragma unroll
        for (int m = 0; m < 4; ++m) {
            const size_t bo = ((size_t)((w * 4 + m) * 4 + sl) * 64 + l) * 8;
            wh[m] = *reinterpret_cast<const bf16x8*>(&w1nh[bo]);
            wl[m] = *reinterpret_cast<const bf16x8*>(&w1nl[bo]);
        }
        bf16x8 fh[4];
        #pragma unroll
        for (int nt = 0; nt < 4; ++nt)
            fh[nt] = *reinterpret_cast<const bf16x8*>(&XF[(sl * 4 + nt) * 512 + l * 8]);
        __builtin_amdgcn_s_setprio(1);
        #pragma unroll
        for (int m = 0; m < 4; ++m)
            #pragma unroll
            for (int nt = 0; nt < 4; ++nt)
                acc[m][nt] = __builtin_amdgcn_mfma_f32_16x16x32_bf16(wh[m], fh[nt], acc[m][nt], 0, 0, 0);
        #pragma unroll
        for (int m = 0; m < 4; ++m)
            #pragma unroll
            for (int nt = 0; nt < 4; ++nt)
                acc[m][nt] = __builtin_amdgcn_mfma_f32_16x16x32_bf16(wl[m], fh[nt], acc[m][nt], 0, 0, 0);
        __builtin_amdgcn_s_setprio(0);
    }

    // ---- epilogue 1: BN + relu -> HF (bf16) ----
    #pragma unroll
    for (int m = 0; m < 4; ++m) {
        const int mt = w * 4 + m;
        const int nb = mt * 16 + l4 * 4;
        float4 b1v = *reinterpret_cast<const float4*>(b1 + nb);
        float4 gv  = *reinterpret_cast<const float4*>(bn_gamma + nb);
        float4 bev = *reinterpret_cast<const float4*>(bn_beta + nb);
        float4 mev = *reinterpret_cast<const float4*>(bn_mean + nb);
        float4 vav = *reinterpret_cast<const float4*>(bn_var + nb);
        float scale[4], shift[4];
        float bb[4] = {b1v.x, b1v.y, b1v.z, b1v.w};
        float gg[4] = {gv.x, gv.y, gv.z, gv.w};
        float be[4] = {bev.x, bev.y, bev.z, bev.w};
        float me[4] = {mev.x, mev.y, mev.z, mev.w};
        float va[4] = {vav.x, vav.y, vav.z, vav.w};
        #pragma unroll
        for (int r = 0; r < 4; ++r) {
            scale[r] = gg[r] * rsqrtf(va[r] + BN_EPS);
            shift[r] = (bb[r] - me[r]) * scale[r] + be[r];
        }
        #pragma unroll
        for (int nt = 0; nt < 4; ++nt) {
            float v[4];
            #pragma unroll
            for (int r = 0; r < 4; ++r)
                v[r] = fmaxf(fmaf(acc[m][nt][r], scale[r], shift[r]), 0.0f);
            u32x2 hv;
            hv[0] = pk2(v[0], v[1]);
            hv[1] = pk2(v[2], v[3]);
            const int base = ((mt >> 1) * 4 + nt) * 512
                           + (l15 + 16 * ((mt & 1) * 2 + (l4 >> 1))) * 8
                           + (l4 & 1) * 4;
            *reinterpret_cast<u32x2*>(&HF[base]) = hv;
        }
    }
    __syncthreads();

    // ---- L2: acc2[m2][nt], wave owns mt2 {2w, 2w+1}, K=256 ----
    f32x4 acc2[2][4];
    #pragma unroll
    for (int m2 = 0; m2 < 2; ++m2)
        #pragma unroll
        for (int nt = 0; nt < 4; ++nt) acc2[m2][nt] = (f32x4){0.f, 0.f, 0.f, 0.f};

    #pragma unroll
    for (int ks2 = 0; ks2 < 8; ++ks2) {
        bf16x8 wh2[2], wl2[2];
        #pragma unroll
        for (int m2 = 0; m2 < 2; ++m2) {
            const size_t bo = ((size_t)((w * 2 + m2) * 8 + ks2) * 64 + l) * 8;
            wh2[m2] = *reinterpret_cast<const bf16x8*>(&w2nh[bo]);
            wl2[m2] = *reinterpret_cast<const bf16x8*>(&w2nl[bo]);
        }
        bf16x8 fh[4];
        #pragma unroll
        for (int nt = 0; nt < 4; ++nt)
            fh[nt] = *reinterpret_cast<const bf16x8*>(&HF[(ks2 * 4 + nt) * 512 + l * 8]);
        __builtin_amdgcn_s_setprio(1);
        #pragma unroll
        for (int m2 = 0; m2 < 2; ++m2)
            #pragma unroll
            for (int nt = 0; nt < 4; ++nt)
                acc2[m2][nt] = __builtin_amdgcn_mfma_f32_16x16x32_bf16(wh2[m2], fh[nt], acc2[m2][nt], 0, 0, 0);
        #pragma unroll
        for (int m2 = 0; m2 < 2; ++m2)
            #pragma unroll
            for (int nt = 0; nt < 4; ++nt)
                acc2[m2][nt] = __builtin_amdgcn_mfma_f32_16x16x32_bf16(wl2[m2], fh[nt], acc2[m2][nt], 0, 0, 0);
        __builtin_amdgcn_s_setprio(0);
    }

    // ---- epilogue 2: z = bf16(relu(acc2 + b2)) -> global ----
    #pragma unroll
    for (int m2 = 0; m2 < 2; ++m2) {
        const int nb2 = (w * 2 + m2) * 16 + l4 * 4;
        float4 b2v = *reinterpret_cast<const float4*>(b2 + nb2);
        float bb[4] = {b2v.x, b2v.y, b2v.z, b2v.w};
        #pragma unroll
        for (int nt = 0; nt < 4; ++nt) {
            const int node = n0 + nt * 16 + l15;
            if (node < N_NODES) {
                float v0 = fmaxf(acc2[m2][nt][0] + bb[0], 0.0f);
                float v1 = fmaxf(acc2[m2][nt][1] + bb[1], 0.0f);
                float v2 = fmaxf(acc2[m2][nt][2] + bb[2], 0.0f);
                float v3 = fmaxf(acc2[m2][nt][3] + bb[3], 0.0f);
                u32x2 hv;
                hv[0] = pk2(v0, v1);
                hv[1] = pk2(v2, v3);
                *reinterpret_cast<u32x2*>(z + (size_t)node * EMB + nb2) = hv;
            }
        }
    }
}

// ---------------------------------------------------------------------------
// Kernel B (MFMA): r13 geometry (64 pairs/block, 4 waves) with ALL FOUR
// feature segments staged up-front into 4x16KB buffers (rebuild reads held
// regs, so no LDS readback needed): ONE barrier then 4 uninterrupted
// run_passes. Barriers 7 -> 5. Math bit-identical to r13 (1-product bf16).
// ---------------------------------------------------------------------------
__global__ __launch_bounds__(256) void pair_mfma_kernel(
    const u16* __restrict__ z,
    const int* __restrict__ pairs,
    const float* __restrict__ logdeg,
    const u16* __restrict__ w1h,
    const u16* __restrict__ w2h,
    const float* __restrict__ SW1, const float* __restrict__ Sb1,
    const float* __restrict__ Sb2,
    const float* __restrict__ SW3, const float* __restrict__ Sb3,
    float* __restrict__ out)
{
    __shared__ __align__(16) u16 F0[8192];   // sd  ch0:64   (ks 0,1,4,5)
    __shared__ __align__(16) u16 F1[8192];   // sd  ch64:128 (ks 2,3,6,7)
    __shared__ __align__(16) u16 F2[8192];   // p|ad ch0:64  (ks 8,9,12,13)
    __shared__ __align__(16) u16 F3[8192];   // p|ad ch64:128(ks 10,11,14,15)
    __shared__ float red[4][4][16];          // 1 KB

    const int t   = threadIdx.x;
    const int w   = t >> 6;        // wave 0..3
    const int l   = t & 63;
    const int l15 = l & 15;
    const int l4  = l >> 4;
    const int p0  = blockIdx.x * PBM;

    // thread (w,l): pair l, channels [w*16, w*16+16) of a 64-ch half.
    const int qb  = (w & 1) * 2;
    const int bS0 = (((w >> 1)) * 4 + l4) * 512 + (l15 + 16 * (qb + 0)) * 8;
    const int bS1 = (((w >> 1)) * 4 + l4) * 512 + (l15 + 16 * (qb + 1)) * 8;
    const int bD0 = ((2 + (w >> 1)) * 4 + l4) * 512 + (l15 + 16 * (qb + 0)) * 8;
    const int bD1 = ((2 + (w >> 1)) * 4 + l4) * 512 + (l15 + 16 * (qb + 1)) * 8;

    const int gp  = (p0 + l < N_PAIRS) ? (p0 + l) : (N_PAIRS - 1);
    const int gsi = pairs[(size_t)gp * 2 + 0];
    const int gdi = pairs[(size_t)gp * 2 + 1];

    // ---- gather both halves (bf16, raw u16x8) ----
    const u16* zs0 = z + (size_t)gsi * EMB + w * 16;
    const u16* zd0 = z + (size_t)gdi * EMB + w * 16;
    u16x8 s00 = *reinterpret_cast<const u16x8*>(zs0);
    u16x8 s01 = *reinterpret_cast<const u16x8*>(zs0 + 8);
    u16x8 d00 = *reinterpret_cast<const u16x8*>(zd0);
    u16x8 d01 = *reinterpret_cast<const u16x8*>(zd0 + 8);
    u16x8 s10 = *reinterpret_cast<const u16x8*>(zs0 + 64);
    u16x8 s11 = *reinterpret_cast<const u16x8*>(zs0 + 72);
    u16x8 d10 = *reinterpret_cast<const u16x8*>(zd0 + 64);
    u16x8 d11 = *reinterpret_cast<const u16x8*>(zd0 + 72);

    // rebuild p = s~*d~, ad = |s~-d~| from held registers
    auto rebuildR = [&](u16x8 sa, u16x8 sb, u16x8 da, u16x8 db, float* pv, float* av) {
        #pragma unroll
        for (int qq = 0; qq < 8; ++qq) {
            const float s = bf2f(sa[qq]);
            const float d = bf2f(da[qq]);
            pv[qq] = s * d;
            av[qq] = fabsf(s - d);
        }
        #pragma unroll
        for (int qq = 0; qq < 8; ++qq) {
            const float s = bf2f(sb[qq]);
            const float d = bf2f(db[qq]);
            pv[8 + qq] = s * d;
            av[8 + qq] = fabsf(s - d);
        }
    };

    // ---- stage ALL FOUR segments up-front ----
    *reinterpret_cast<u16x8*>(&F0[bS0]) = s00;
    *reinterpret_cast<u16x8*>(&F0[bS1]) = s01;
    *reinterpret_cast<u16x8*>(&F0[bD0]) = d00;
    *reinterpret_cast<u16x8*>(&F0[bD1]) = d01;
    *reinterpret_cast<u16x8*>(&F1[bS0]) = s10;
    *reinterpret_cast<u16x8*>(&F1[bS1]) = s11;
    *reinterpret_cast<u16x8*>(&F1[bD0]) = d10;
    *reinterpret_cast<u16x8*>(&F1[bD1]) = d11;
    {
        float pv[16], av[16];
        rebuildR(s00, s01, d00, d01, pv, av);
        store8(F2, bS0, pv + 0);
        store8(F2, bS1, pv + 8);
        store8(F2, bD0, av + 0);
        store8(F2, bD1, av + 8);
        rebuildR(s10, s11, d10, d11, pv, av);
        store8(F3, bS0, pv + 0);
        store8(F3, bS1, pv + 8);
        store8(F3, bD0, av + 0);
        store8(F3, bD1, av + 8);
    }

    // ---- prefetch epilogue-1 gather data ----
    float ldS[4], ldD[4];
    #pragma unroll
    for (int nt = 0; nt < 4; ++nt) {
        const int pidx = (p0 + nt * 16 + l15 < N_PAIRS) ? (p0 + nt * 16 + l15) : (N_PAIRS - 1);
        ldS[nt] = logdeg[pairs[(size_t)pidx * 2 + 0]];
        ldD[nt] = logdeg[pairs[(size_t)pidx * 2 + 1]];
    }

    __syncthreads();   // bar1: all features staged

    f32x4 acc[4][4];
    #pragma unroll
    for (int m = 0; m < 4; ++m)
        #pragma unroll
        for (int nt = 0; nt < 4; ++nt) acc[m][nt] = (f32x4){0.f, 0.f, 0.f, 0.f};

    // one 128-K segment; weight register dbuf across sl; 1-product
    auto run_pass = [&](const u16* buf, int k0, int k1, int k2, int k3) {
        const int ksg[4] = {k0, k1, k2, k3};
        bf16x8 wh[2][4];
        #pragma unroll
        for (int m = 0; m < 4; ++m) {
            const size_t bo = ((size_t)((w * 4 + m) * 16 + ksg[0]) * 64 + l) * 8;
            wh[0][m] = *reinterpret_cast<const bf16x8*>(&w1h[bo]);
        }
        #pragma unroll
        for (int sl = 0; sl < 4; ++sl) {
            const int cur = sl & 1;
            if (sl < 3) {
                #pragma unroll
                for (int m = 0; m < 4; ++m) {
                    const size_t bo = ((size_t)((w * 4 + m) * 16 + ksg[sl + 1]) * 64 + l) * 8;
                    wh[cur ^ 1][m] = *reinterpret_cast<const bf16x8*>(&w1h[bo]);
                }
            }
            #pragma unroll
            for (int nh = 0; nh < 2; ++nh) {
                bf16x8 fh[2];
                #pragma unroll
                for (int e = 0; e < 2; ++e)
                    fh[e] = *reinterpret_cast<const bf16x8*>(&buf[(sl * 4 + nh * 2 + e) * 512 + l * 8]);
                __builtin_amdgcn_s_setprio(1);
                #pragma unroll
                for (int m = 0; m < 4; ++m)
                    #pragma unroll
                    for (int e = 0; e < 2; ++e)
                        acc[m][nh * 2 + e] = __builtin_amdgcn_mfma_f32_16x16x32_bf16(wh[cur][m], fh[e], acc[m][nh * 2 + e], 0, 0, 0);
                __builtin_amdgcn_s_setprio(0);
            }
        }
    };

    // ---- layer 1: four uninterrupted passes ----
    run_pass(F0, 0, 1, 4, 5);
    run_pass(F2, 8, 9, 12, 13);
    run_pass(F1, 2, 3, 6, 7);
    run_pass(F3, 10, 11, 14, 15);
    __syncthreads();   // bar2: L1 done; F0/F1 reusable

    // ---- layer 2 ----
    f32x4 acc2[2][4];
    #pragma unroll
    for (int m2 = 0; m2 < 2; ++m2)
        #pragma unroll
        for (int nt = 0; nt < 4; ++nt) acc2[m2][nt] = (f32x4){0.f, 0.f, 0.f, 0.f};

    auto epi1 = [&](u16* buf, int g) {
        #pragma unroll
        for (int mm = 0; mm < 2; ++mm) {
            const int m  = 2 * g + mm;
            const int mt = w * 4 + m;
            const int nb = mt * 16 + l4 * 4;
            float sb[4], wa[4], wb[4];
            *reinterpret_cast<float4*>(sb) = *reinterpret_cast<const float4*>(&Sb1[nb]);
            *reinterpret_cast<float4*>(wa) = *reinterpret_cast<const float4*>(&SW1[(size_t)512 * HID + nb]);
            *reinterpret_cast<float4*>(wb) = *reinterpret_cast<const float4*>(&SW1[(size_t)513 * HID + nb]);
            #pragma unroll
            for (int nt = 0; nt < 4; ++nt) {
                float v[4];
                #pragma unroll
                for (int r = 0; r < 4; ++r) {
                    float x0 = acc[m][nt][r] + sb[r];
                    x0 = fmaf(ldS[nt], wa[r], x0);
                    x0 = fmaf(ldD[nt], wb[r], x0);
                    v[r] = fmaxf(x0, 0.0f);
                }
                u32x2 hv;
                hv[0] = pk2(v[0], v[1]);
                hv[1] = pk2(v[2], v[3]);
                const int base = (w * 4 + nt) * 512
                               + (l15 + 16 * ((m & 1) * 2 + (l4 >> 1))) * 8
                               + (l4 & 1) * 4;
                *reinterpret_cast<u32x2*>(&buf[base]) = hv;
            }
        }
    };

    auto mfma2 = [&](const u16* buf, int g) {
        #pragma unroll
        for (int cs = 0; cs < 4; ++cs) {
            const int ks2 = cs * 2 + g;
            bf16x8 wh2[2];
            #pragma unroll
            for (int m2 = 0; m2 < 2; ++m2) {
                const size_t bo = ((size_t)((w * 2 + m2) * 8 + ks2) * 64 + l) * 8;
                wh2[m2] = *reinterpret_cast<const bf16x8*>(&w2h[bo]);
            }
            #pragma unroll
            for (int nh = 0; nh < 2; ++nh) {
                bf16x8 fh[2];
                #pragma unroll
                for (int e = 0; e < 2; ++e)
                    fh[e] = *reinterpret_cast<const bf16x8*>(&buf[(cs * 4 + nh * 2 + e) * 512 + l * 8]);
                __builtin_amdgcn_s_setprio(1);
                #pragma unroll
                for (int m2 = 0; m2 < 2; ++m2)
                    #pragma unroll
                    for (int e = 0; e < 2; ++e)
                        acc2[m2][nh * 2 + e] = __builtin_amdgcn_mfma_f32_16x16x32_bf16(wh2[m2], fh[e], acc2[m2][nh * 2 + e], 0, 0, 0);
                __builtin_amdgcn_s_setprio(0);
            }
        }
    };

    epi1(F0, 0);
    __syncthreads();         // bar3: F0 s1-frags visible
    epi1(F1, 1);             // overlaps mfma2(F0)
    mfma2(F0, 0);
    __syncthreads();         // bar4: F1 s1-frags visible
    mfma2(F1, 1);

    // ---- epilogue 2 + layer 3 ----
    {
        float part[4] = {0.f, 0.f, 0.f, 0.f};
        #pragma unroll
        for (int m2 = 0; m2 < 2; ++m2) {
            const int nb2 = (w * 2 + m2) * 16 + l4 * 4;
            float sb[4], w3[4];
            *reinterpret_cast<float4*>(sb) = *reinterpret_cast<const float4*>(&Sb2[nb2]);
            *reinterpret_cast<float4*>(w3) = *reinterpret_cast<const float4*>(&SW3[nb2]);
            #pragma unroll
            for (int nt = 0; nt < 4; ++nt)
                #pragma unroll
                for (int r = 0; r < 4; ++r)
                    part[nt] = fmaf(fmaxf(acc2[m2][nt][r] + sb[r], 0.0f), w3[r], part[nt]);
        }
        #pragma unroll
        for (int nt = 0; nt < 4; ++nt) {
            part[nt] += __shfl_xor(part[nt], 16);
            part[nt] += __shfl_xor(part[nt], 32);
        }
        if (l < 16) {
            #pragma unroll
            for (int nt = 0; nt < 4; ++nt) red[w][nt][l15] = part[nt];
        }
    }
    __syncthreads();   // bar5

    if (t < 64) {
        const int nt = t >> 4, pp = t & 15;
        float v = red[0][nt][pp] + red[1][nt][pp] + red[2][nt][pp] + red[3][nt][pp] + Sb3[0];
        if (isnan(v)) v = 0.0f;
        else if (isinf(v)) v = (v > 0.0f) ? 20.0f : -20.0f;
        const int pidx = p0 + nt * 16 + pp;
        if (pidx < N_PAIRS) out[pidx] = v;
    }
}

// ---------------------------------------------------------------------------
extern "C" void kernel_launch(void* const* d_in, const int* in_sizes, int n_in,
                              void* d_out, int out_size, void* d_ws, size_t ws_size,
                              hipStream_t stream)
{
    const float* x        = (const float*)d_in[0];
    // d_in[1] = edge_index : unused by the reference
    const int*   pairs    = (const int*)d_in[2];
    const float* x_mean   = (const float*)d_in[3];
    const float* x_std    = (const float*)d_in[4];
    const float* logdeg   = (const float*)d_in[5];
    const float* W1       = (const float*)d_in[6];
    const float* b1       = (const float*)d_in[7];
    const float* bn_gamma = (const float*)d_in[8];
    const float* bn_beta  = (const float*)d_in[9];
    const float* bn_mean  = (const float*)d_in[10];
    const float* bn_var   = (const float*)d_in[11];
    const float* W2       = (const float*)d_in[12];
    const float* b2       = (const float*)d_in[13];
    const float* SW1      = (const float*)d_in[14];
    const float* Sb1      = (const float*)d_in[15];
    const float* SW2      = (const float*)d_in[16];
    const float* Sb2      = (const float*)d_in[17];
    const float* SW3      = (const float*)d_in[18];
    const float* Sb3      = (const float*)d_in[19];

    float* outp = (float*)d_out;

    // ws layout (z bf16: 25,600,000 B)
    char* wsb = (char*)d_ws;
    u16* zbuf = (u16*)wsb;
    u16* w1h  = (u16*)(wsb + 25600000);                 // 262144 B
    u16* w2h  = (u16*)(wsb + 25862144);                 // 65536 B
    u16* w1nh = (u16*)(wsb + 25927680);                 // 65536 B
    u16* w1nl = (u16*)(wsb + 25993216);                 // 65536 B
    u16* w2nh = (u16*)(wsb + 26058752);                 // 65536 B
    u16* w2nl = (u16*)(wsb + 26124288);                 // 65536 B (end 26,189,824)

    prep_weights<<<896, 256, 0, stream>>>(SW1, SW2, W1, W2,
                                          w1h, w2h,
                                          w1nh, w1nl, w2nh, w2nl);

    node_mfma_kernel<<<(N_NODES + 63) / 64, 256, 0, stream>>>(
        x, x_mean, x_std, b1, bn_gamma, bn_beta, bn_mean, bn_var, b2,
        w1nh, w1nl, w2nh, w2nl, zbuf);

    pair_mfma_kernel<<<(N_PAIRS + PBM - 1) / PBM, 256, 0, stream>>>(
        zbuf, pairs, logdeg, w1h, w2h, SW1, Sb1, Sb2, SW3, Sb3, outp);
}